// Round 1
// baseline (404.715 us; speedup 1.0000x reference)
//
#include <hip/hip_runtime.h>
#include <math.h>

#define BB   2
#define NN   2048
#define DDIM 512
#define HH   8
#define DH   64
#define MTOT (BB*NN)   // 4096

__device__ __forceinline__ float softplus_f(float x) {
    return x > 20.f ? x : log1pf(expf(x));
}

// ---------------------------------------------------------------------------
// Q/K/V projection: Y = x @ W.T, written in [B,H,N,dh] layout.
// blockIdx.z selects Wq/Wk/Wv. 64x64 tile, BK=16, 4x4 micro-tile.
// ---------------------------------------------------------------------------
__global__ __launch_bounds__(256, 2)
void proj_gemm(const float* __restrict__ X,
               const float* __restrict__ Wq,
               const float* __restrict__ Wk,
               const float* __restrict__ Wv,
               float* __restrict__ Qo, float* __restrict__ Ko, float* __restrict__ Vo)
{
    const int which = blockIdx.z;
    const float* W = (which == 0) ? Wq : ((which == 1) ? Wk : Wv);
    float* Y = (which == 0) ? Qo : ((which == 1) ? Ko : Vo);

    const int m0 = blockIdx.x * 64;   // row tile over 4096
    const int h  = blockIdx.y;        // head = 64-col tile over 512

    __shared__ float As[16][68];      // [k][m] transposed
    __shared__ float Bs[16][68];      // [k][n] transposed

    const int tid = threadIdx.x;
    const int lm  = tid >> 2;         // 0..63
    const int lk4 = (tid & 3) << 2;   // 0,4,8,12
    const int tx  = tid & 15;
    const int ty  = tid >> 4;

    float acc[4][4] = {};

    for (int k0 = 0; k0 < DDIM; k0 += 16) {
        float4 xa = *(const float4*)(X + (size_t)(m0 + lm) * DDIM + k0 + lk4);
        float4 wb = *(const float4*)(W + (size_t)(h * 64 + lm) * DDIM + k0 + lk4);
        As[lk4+0][lm] = xa.x; As[lk4+1][lm] = xa.y; As[lk4+2][lm] = xa.z; As[lk4+3][lm] = xa.w;
        Bs[lk4+0][lm] = wb.x; Bs[lk4+1][lm] = wb.y; Bs[lk4+2][lm] = wb.z; Bs[lk4+3][lm] = wb.w;
        __syncthreads();
        #pragma unroll
        for (int kk = 0; kk < 16; ++kk) {
            float4 a = *(const float4*)&As[kk][ty << 2];
            float4 b = *(const float4*)&Bs[kk][tx << 2];
            float av[4] = {a.x, a.y, a.z, a.w};
            float bv[4] = {b.x, b.y, b.z, b.w};
            #pragma unroll
            for (int i = 0; i < 4; ++i)
                #pragma unroll
                for (int j = 0; j < 4; ++j)
                    acc[i][j] = fmaf(av[i], bv[j], acc[i][j]);
        }
        __syncthreads();
    }

    #pragma unroll
    for (int i = 0; i < 4; ++i) {
        const int m = m0 + (ty << 2) + i;
        const int b = m >> 11;          // /2048
        const int n = m & 2047;
        float4 o = make_float4(acc[i][0], acc[i][1], acc[i][2], acc[i][3]);
        *(float4*)(Y + (((size_t)(b * HH + h) * NN + n) << 6) + (tx << 2)) = o;
    }
}

// ---------------------------------------------------------------------------
// Row norms: ||q||^2 and ||k||^2 per (b,h,n). blockIdx.y: 0 -> q, 1 -> k.
// ---------------------------------------------------------------------------
__global__ __launch_bounds__(256)
void norms_kernel(const float* __restrict__ Q, const float* __restrict__ K,
                  float* __restrict__ QN, float* __restrict__ KN)
{
    const int row = blockIdx.x * 64 + (threadIdx.x >> 2);
    const int seg = (threadIdx.x & 3) << 4;
    const float* src = (blockIdx.y == 0) ? Q : K;
    float* dst = (blockIdx.y == 0) ? QN : KN;
    const float* p = src + ((size_t)row << 6) + seg;
    float s = 0.f;
    #pragma unroll
    for (int t = 0; t < 16; t += 4) {
        float4 xv = *(const float4*)(p + t);
        s += xv.x*xv.x + xv.y*xv.y + xv.z*xv.z + xv.w*xv.w;
    }
    s += __shfl_xor(s, 1);
    s += __shfl_xor(s, 2);
    if ((threadIdx.x & 3) == 0) dst[row] = s;
}

// ---------------------------------------------------------------------------
// Flash-style causal hyperbolic attention, fp32. 64-query tiles.
// Block id mapping balances causal work: ids c and c+256 sum to 33 tiles.
// ---------------------------------------------------------------------------
__global__ __launch_bounds__(256, 2)
void attn_kernel(const float* __restrict__ Q, const float* __restrict__ K,
                 const float* __restrict__ V, const float* __restrict__ QN,
                 const float* __restrict__ KN, const float* __restrict__ pLC,
                 const float* __restrict__ pLB, float* __restrict__ AO)
{
    __shared__ float Qs[64][68];   // [d][row]
    __shared__ float Ks[64][68];   // [d][key]
    __shared__ float Vs[64][68];   // [key][d]
    __shared__ float Ps[64][68];   // [row][key]
    __shared__ float qn_s[64];
    __shared__ float kn_s[64];

    const int id = blockIdx.x;
    int bh, qt;
    if (id < 256) { qt = id >> 3;              bh = id & 7; }
    else          { int t = id - 256; qt = 31 - (t >> 3); bh = 8 + (t & 7); }

    const int tid = threadIdx.x;
    const int lm  = tid >> 2;
    const int lq  = tid & 3;
    const int tx  = tid & 15;
    const int ty  = tid >> 4;

    const float c    = softplus_f(pLC[0]);
    const float beta = softplus_f(pLB[0]) + 0.5f;

    const size_t base = ((size_t)bh * NN) << 6;   // bh * N * 64

    // Load Q tile transposed into LDS
    {
        const float* qp = Q + base + ((size_t)((qt << 6) + lm) << 6);
        #pragma unroll
        for (int it = 0; it < 4; ++it) {
            const int d4 = (lq << 2) + (it << 4);
            float4 xv = *(const float4*)(qp + d4);
            Qs[d4+0][lm] = xv.x; Qs[d4+1][lm] = xv.y;
            Qs[d4+2][lm] = xv.z; Qs[d4+3][lm] = xv.w;
        }
        if (tid < 64) qn_s[tid] = QN[bh * NN + (qt << 6) + tid];
    }

    float m_st[4], l_st[4], O[4][4];
    #pragma unroll
    for (int i = 0; i < 4; ++i) {
        m_st[i] = -INFINITY; l_st[i] = 0.f;
        #pragma unroll
        for (int j = 0; j < 4; ++j) O[i][j] = 0.f;
    }

    __syncthreads();

    for (int kt = 0; kt <= qt; ++kt) {
        const float* kp = K + base + ((size_t)((kt << 6) + lm) << 6);
        const float* vp = V + base + ((size_t)((kt << 6) + lm) << 6);
        #pragma unroll
        for (int it = 0; it < 4; ++it) {
            const int d4 = (lq << 2) + (it << 4);
            float4 kv = *(const float4*)(kp + d4);
            Ks[d4+0][lm] = kv.x; Ks[d4+1][lm] = kv.y;
            Ks[d4+2][lm] = kv.z; Ks[d4+3][lm] = kv.w;
            float4 vv = *(const float4*)(vp + d4);
            *(float4*)&Vs[lm][d4] = vv;
        }
        if (tid < 64) kn_s[tid] = KN[bh * NN + (kt << 6) + tid];
        __syncthreads();

        // S = Q . K^T  (raw dot products)
        float acc[4][4] = {};
        #pragma unroll 16
        for (int d = 0; d < 64; ++d) {
            float4 a = *(const float4*)&Qs[d][ty << 2];
            float4 b = *(const float4*)&Ks[d][tx << 2];
            float av[4] = {a.x, a.y, a.z, a.w};
            float bv[4] = {b.x, b.y, b.z, b.w};
            #pragma unroll
            for (int i = 0; i < 4; ++i)
                #pragma unroll
                for (int j = 0; j < 4; ++j)
                    acc[i][j] = fmaf(av[i], bv[j], acc[i][j]);
        }

        // hyperbolic distance -> scores (in place in acc)
        const bool diag = (kt == qt);
        float mrow[4];
        #pragma unroll
        for (int i = 0; i < 4; ++i) {
            const float qn = qn_s[(ty << 2) + i];
            float mloc = -INFINITY;
            #pragma unroll
            for (int j = 0; j < 4; ++j) {
                const float kn = kn_s[(tx << 2) + j];
                const float sum_n = qn + kn;
                float diff = fmaxf(fmaf(-2.f, acc[i][j], sum_n), 0.f);
                float h2 = fmaf(c, sum_n, 1.f);
                float s = -beta * sqrtf((diff + 1e-8f) * h2);
                if (diag && ((tx << 2) + j > (ty << 2) + i)) s = -INFINITY;
                acc[i][j] = s;
                mloc = fmaxf(mloc, s);
            }
            mrow[i] = mloc;
        }

        // online softmax update (rows owned by 16-lane groups along tx)
        #pragma unroll
        for (int i = 0; i < 4; ++i) {
            float m = mrow[i];
            m = fmaxf(m, __shfl_xor(m, 1));
            m = fmaxf(m, __shfl_xor(m, 2));
            m = fmaxf(m, __shfl_xor(m, 4));
            m = fmaxf(m, __shfl_xor(m, 8));
            const float mnew  = fmaxf(m_st[i], m);
            const float alpha = __expf(m_st[i] - mnew);   // first tile: exp(-inf)=0
            float rs = 0.f;
            #pragma unroll
            for (int j = 0; j < 4; ++j) {
                float p = __expf(acc[i][j] - mnew);       // masked -inf -> 0
                acc[i][j] = p;
                rs += p;
            }
            rs += __shfl_xor(rs, 1);
            rs += __shfl_xor(rs, 2);
            rs += __shfl_xor(rs, 4);
            rs += __shfl_xor(rs, 8);
            l_st[i] = l_st[i] * alpha + rs;
            m_st[i] = mnew;
            #pragma unroll
            for (int j = 0; j < 4; ++j) O[i][j] *= alpha;
            *(float4*)&Ps[(ty << 2) + i][tx << 2] =
                make_float4(acc[i][0], acc[i][1], acc[i][2], acc[i][3]);
        }
        __syncthreads();

        // O += P . V
        #pragma unroll 16
        for (int j2 = 0; j2 < 64; ++j2) {
            float4 vv = *(const float4*)&Vs[j2][tx << 2];
            const float p0 = Ps[(ty << 2) + 0][j2];
            const float p1 = Ps[(ty << 2) + 1][j2];
            const float p2 = Ps[(ty << 2) + 2][j2];
            const float p3 = Ps[(ty << 2) + 3][j2];
            O[0][0] = fmaf(p0, vv.x, O[0][0]); O[0][1] = fmaf(p0, vv.y, O[0][1]);
            O[0][2] = fmaf(p0, vv.z, O[0][2]); O[0][3] = fmaf(p0, vv.w, O[0][3]);
            O[1][0] = fmaf(p1, vv.x, O[1][0]); O[1][1] = fmaf(p1, vv.y, O[1][1]);
            O[1][2] = fmaf(p1, vv.z, O[1][2]); O[1][3] = fmaf(p1, vv.w, O[1][3]);
            O[2][0] = fmaf(p2, vv.x, O[2][0]); O[2][1] = fmaf(p2, vv.y, O[2][1]);
            O[2][2] = fmaf(p2, vv.z, O[2][2]); O[2][3] = fmaf(p2, vv.w, O[2][3]);
            O[3][0] = fmaf(p3, vv.x, O[3][0]); O[3][1] = fmaf(p3, vv.y, O[3][1]);
            O[3][2] = fmaf(p3, vv.z, O[3][2]); O[3][3] = fmaf(p3, vv.w, O[3][3]);
        }
        __syncthreads();
    }

    // epilogue: normalize and store [B,H,N,dh]
    #pragma unroll
    for (int i = 0; i < 4; ++i) {
        const float inv = 1.f / l_st[i];
        const int r = (qt << 6) + (ty << 2) + i;
        *(float4*)(AO + base + ((size_t)r << 6) + (tx << 2)) =
            make_float4(O[i][0] * inv, O[i][1] * inv, O[i][2] * inv, O[i][3] * inv);
    }
}

// ---------------------------------------------------------------------------
// Output projection: out = attn_out @ Wo.T, reading [B,H,N,dh], writing [B,N,D]
// ---------------------------------------------------------------------------
__global__ __launch_bounds__(256, 2)
void out_gemm(const float* __restrict__ AO, const float* __restrict__ Wo,
              float* __restrict__ Out)
{
    const int m0 = blockIdx.x * 64;
    const int n0 = blockIdx.y * 64;

    __shared__ float As[16][68];
    __shared__ float Bs[16][68];

    const int tid = threadIdx.x;
    const int lm  = tid >> 2;
    const int lk4 = (tid & 3) << 2;
    const int tx  = tid & 15;
    const int ty  = tid >> 4;

    float acc[4][4] = {};

    const int mrow = m0 + lm;
    const int b = mrow >> 11;
    const int n = mrow & 2047;

    for (int k0 = 0; k0 < DDIM; k0 += 16) {
        const int e = k0 + lk4;         // h = e>>6 constant across the float4
        float4 xa = *(const float4*)(AO + (((size_t)(b * HH + (e >> 6)) * NN + n) << 6) + (e & 63));
        float4 wb = *(const float4*)(Wo + (size_t)(n0 + lm) * DDIM + k0 + lk4);
        As[lk4+0][lm] = xa.x; As[lk4+1][lm] = xa.y; As[lk4+2][lm] = xa.z; As[lk4+3][lm] = xa.w;
        Bs[lk4+0][lm] = wb.x; Bs[lk4+1][lm] = wb.y; Bs[lk4+2][lm] = wb.z; Bs[lk4+3][lm] = wb.w;
        __syncthreads();
        #pragma unroll
        for (int kk = 0; kk < 16; ++kk) {
            float4 a = *(const float4*)&As[kk][ty << 2];
            float4 b4 = *(const float4*)&Bs[kk][tx << 2];
            float av[4] = {a.x, a.y, a.z, a.w};
            float bv[4] = {b4.x, b4.y, b4.z, b4.w};
            #pragma unroll
            for (int i = 0; i < 4; ++i)
                #pragma unroll
                for (int j = 0; j < 4; ++j)
                    acc[i][j] = fmaf(av[i], bv[j], acc[i][j]);
        }
        __syncthreads();
    }

    #pragma unroll
    for (int i = 0; i < 4; ++i) {
        const int m = m0 + (ty << 2) + i;
        *(float4*)(Out + (size_t)m * DDIM + n0 + (tx << 2)) =
            make_float4(acc[i][0], acc[i][1], acc[i][2], acc[i][3]);
    }
}

// ---------------------------------------------------------------------------
extern "C" void kernel_launch(void* const* d_in, const int* in_sizes, int n_in,
                              void* d_out, int out_size, void* d_ws, size_t ws_size,
                              hipStream_t stream)
{
    const float* x        = (const float*)d_in[0];
    const float* Wq       = (const float*)d_in[1];
    const float* Wk       = (const float*)d_in[2];
    const float* Wv       = (const float*)d_in[3];
    const float* Wo       = (const float*)d_in[4];
    const float* log_c    = (const float*)d_in[5];
    const float* log_beta = (const float*)d_in[6];
    float* out = (float*)d_out;

    const size_t QKV = (size_t)BB * HH * NN * DH;   // 2,097,152 floats
    float* q  = (float*)d_ws;
    float* k  = q  + QKV;
    float* v  = k  + QKV;
    float* ao = v  + QKV;
    float* qn = ao + QKV;
    float* kn = qn + (size_t)BB * HH * NN;

    proj_gemm  <<<dim3(MTOT / 64, HH, 3), 256, 0, stream>>>(x, Wq, Wk, Wv, q, k, v);
    norms_kernel<<<dim3((BB * HH * NN) / 64, 2), 256, 0, stream>>>(q, k, qn, kn);
    attn_kernel<<<dim3(512), 256, 0, stream>>>(q, k, v, qn, kn, log_c, log_beta, ao);
    out_gemm   <<<dim3(MTOT / 64, DDIM / 64), 256, 0, stream>>>(ao, Wo, out);
}

// Round 4
// 318.299 us; speedup vs baseline: 1.2715x; 1.2715x over previous
//
#include <hip/hip_runtime.h>
#include <math.h>

#define BB   2
#define NN   2048
#define DDIM 512
#define HH   8
#define DH   64
#define MTOT (BB*NN)   // 4096
#define LDK  72        // ushort stride for 64-wide bf16 LDS rows (144 B: 2-way conflicts only)

typedef __attribute__((ext_vector_type(8))) short bf16x8;   // 8 bf16 = 4 VGPRs
typedef __attribute__((ext_vector_type(4))) float f32x4;

__device__ __forceinline__ float softplus_f(float x) {
    return x > 20.f ? x : log1pf(expf(x));
}
__device__ __forceinline__ unsigned short f2bf(float x) {   // round-to-nearest-even
    union { float f; unsigned u; } v; v.f = x;
    unsigned r = v.u + 0x7fffu + ((v.u >> 16) & 1u);
    return (unsigned short)(r >> 16);
}
__device__ __forceinline__ float bf2f(unsigned short h) {
    union { unsigned u; float f; } v; v.u = ((unsigned)h) << 16; return v.f;
}

// ---------------------------------------------------------------------------
// Q/K/V projection: Y = x @ W.T (fp32 math). Epilogue emits bf16 hi/lo splits
// for Q,K (natural [B,H,N,dh]), bf16 V, and exact fp32 row norms qn/kn.
// ---------------------------------------------------------------------------
__global__ __launch_bounds__(256, 2)
void proj_gemm(const float* __restrict__ X,
               const float* __restrict__ Wq,
               const float* __restrict__ Wk,
               const float* __restrict__ Wv,
               unsigned short* __restrict__ Qhi, unsigned short* __restrict__ Qlo,
               unsigned short* __restrict__ Khi, unsigned short* __restrict__ Klo,
               unsigned short* __restrict__ Vb,
               float* __restrict__ QN, float* __restrict__ KN)
{
    const int which = blockIdx.z;
    const float* W = (which == 0) ? Wq : ((which == 1) ? Wk : Wv);

    const int m0 = blockIdx.x * 64;
    const int h  = blockIdx.y;

    __shared__ float As[16][68];
    __shared__ float Bs[16][68];

    const int tid = threadIdx.x;
    const int lm  = tid >> 2;
    const int lk4 = (tid & 3) << 2;
    const int tx  = tid & 15;
    const int ty  = tid >> 4;

    float acc[4][4] = {};

    for (int k0 = 0; k0 < DDIM; k0 += 16) {
        float4 xa = *(const float4*)(X + (size_t)(m0 + lm) * DDIM + k0 + lk4);
        float4 wb = *(const float4*)(W + (size_t)(h * 64 + lm) * DDIM + k0 + lk4);
        As[lk4+0][lm] = xa.x; As[lk4+1][lm] = xa.y; As[lk4+2][lm] = xa.z; As[lk4+3][lm] = xa.w;
        Bs[lk4+0][lm] = wb.x; Bs[lk4+1][lm] = wb.y; Bs[lk4+2][lm] = wb.z; Bs[lk4+3][lm] = wb.w;
        __syncthreads();
        #pragma unroll
        for (int kk = 0; kk < 16; ++kk) {
            float4 a = *(const float4*)&As[kk][ty << 2];
            float4 b = *(const float4*)&Bs[kk][tx << 2];
            float av[4] = {a.x, a.y, a.z, a.w};
            float bv[4] = {b.x, b.y, b.z, b.w};
            #pragma unroll
            for (int i = 0; i < 4; ++i)
                #pragma unroll
                for (int j = 0; j < 4; ++j)
                    acc[i][j] = fmaf(av[i], bv[j], acc[i][j]);
        }
        __syncthreads();
    }

    #pragma unroll
    for (int i = 0; i < 4; ++i) {
        const int m = m0 + (ty << 2) + i;
        const int b = m >> 11;
        const int n = m & 2047;
        const size_t rowbase = (((size_t)(b * HH + h) * NN + n) << 6) + (tx << 2);

        if (which == 2) {
            ushort4 hv = make_ushort4(f2bf(acc[i][0]), f2bf(acc[i][1]),
                                      f2bf(acc[i][2]), f2bf(acc[i][3]));
            *(ushort4*)(Vb + rowbase) = hv;
        } else {
            ushort4 hv, lv;
            {
                unsigned short h0 = f2bf(acc[i][0]); unsigned short l0 = f2bf(acc[i][0] - bf2f(h0));
                unsigned short h1 = f2bf(acc[i][1]); unsigned short l1 = f2bf(acc[i][1] - bf2f(h1));
                unsigned short h2 = f2bf(acc[i][2]); unsigned short l2 = f2bf(acc[i][2] - bf2f(h2));
                unsigned short h3 = f2bf(acc[i][3]); unsigned short l3 = f2bf(acc[i][3] - bf2f(h3));
                hv = make_ushort4(h0, h1, h2, h3);
                lv = make_ushort4(l0, l1, l2, l3);
            }
            float s = acc[i][0]*acc[i][0] + acc[i][1]*acc[i][1]
                    + acc[i][2]*acc[i][2] + acc[i][3]*acc[i][3];
            s += __shfl_xor(s, 1);
            s += __shfl_xor(s, 2);
            s += __shfl_xor(s, 4);
            s += __shfl_xor(s, 8);
            if (which == 0) {
                *(ushort4*)(Qhi + rowbase) = hv;
                *(ushort4*)(Qlo + rowbase) = lv;
                if (tx == 0) QN[(size_t)(b * HH + h) * NN + n] = s;
            } else {
                *(ushort4*)(Khi + rowbase) = hv;
                *(ushort4*)(Klo + rowbase) = lv;
                if (tx == 0) KN[(size_t)(b * HH + h) * NN + n] = s;
            }
        }
    }
}

// ---------------------------------------------------------------------------
// V transpose: Vb [B,H,N,64] bf16 -> Vt [B,H,64,N] bf16 (for MFMA B-fragments)
// ---------------------------------------------------------------------------
__global__ __launch_bounds__(256)
void v_transpose(const unsigned short* __restrict__ Vb, unsigned short* __restrict__ Vt)
{
    __shared__ unsigned short T[64 * LDK];
    const int id = blockIdx.x;          // 512 = 16 bh * 32 n-tiles
    const int bh = id >> 5, nt = id & 31;
    const size_t ibase = (((size_t)bh * NN + nt * 64) << 6);
    const int row = threadIdx.x >> 2, ch = threadIdx.x & 3;

    #pragma unroll
    for (int half = 0; half < 2; ++half) {
        const int col = ch * 8 + half * 32;
        *(uint4*)&T[row * LDK + col] = *(const uint4*)(Vb + ibase + (row << 6) + col);
    }
    __syncthreads();

    const size_t obase = (size_t)bh * 64 * NN;
    #pragma unroll
    for (int half = 0; half < 2; ++half) {
        const int col = ch * 8 + half * 32;   // n-offset within tile
        union { unsigned short u[8]; uint4 v; } tmp;
        #pragma unroll
        for (int j = 0; j < 8; ++j) tmp.u[j] = T[(col + j) * LDK + row];
        *(uint4*)(Vt + obase + (size_t)row * NN + nt * 64 + col) = tmp.v;
    }
}

// ---------------------------------------------------------------------------
// MFMA flash attention, causal hyperbolic scores. 64 q-rows/block, 4 waves,
// each wave owns a 16-row stripe. QK^T = Qhi*Khi + Qhi*Klo + Qlo*Khi.
// C/D layout col=lane&15, row=(lane>>4)*4+reg (validated on-HW: round-3
// attribution probe produced output identical to this hardcoded mapping).
// NOTE: no "diagonal diff=0" shortcut — q_i and k_i are different projections
// of x_i, so ||q_i - k_i||^2 is NOT zero (round-2/3 bug).
// ---------------------------------------------------------------------------
__global__ __launch_bounds__(256, 2)
void attn_mfma(const unsigned short* __restrict__ Qhi, const unsigned short* __restrict__ Qlo,
               const unsigned short* __restrict__ Khi, const unsigned short* __restrict__ Klo,
               const unsigned short* __restrict__ Vt,
               const float* __restrict__ QN, const float* __restrict__ KN,
               const float* __restrict__ pLC, const float* __restrict__ pLB,
               float* __restrict__ AO)
{
    __shared__ unsigned short Kh_s[64 * LDK];
    __shared__ unsigned short Kl_s[64 * LDK];
    __shared__ unsigned short Vt_s[64 * LDK];
    __shared__ unsigned short P_s [64 * LDK];
    __shared__ float kn_s[64];
    __shared__ float qn_s[64];

    const int id = blockIdx.x;
    int bh, qt;
    if (id < 256) { qt = id >> 3;                 bh = id & 7; }
    else          { int t2 = id - 256; qt = 31 - (t2 >> 3); bh = 8 + (t2 & 7); }

    const int tid  = threadIdx.x;
    const int w    = tid >> 6;       // wave id: rows 16w..16w+15
    const int lane = tid & 63;
    const int lx   = lane & 15;
    const int q4   = lane >> 4;

    const float hc   = softplus_f(pLC[0]);
    const float beta = softplus_f(pLB[0]) + 0.5f;

    const size_t base = ((size_t)bh * NN) << 6;

    // Q fragments held in registers for the whole block (A-layout: m=lx, k=q4*8+j)
    const unsigned short* qrh = Qhi + base + ((size_t)(qt * 64 + w * 16 + lx) << 6) + q4 * 8;
    const unsigned short* qrl = Qlo + base + ((size_t)(qt * 64 + w * 16 + lx) << 6) + q4 * 8;
    const bf16x8 qh0 = *(const bf16x8*)(qrh);
    const bf16x8 qh1 = *(const bf16x8*)(qrh + 32);
    const bf16x8 ql0 = *(const bf16x8*)(qrl);
    const bf16x8 ql1 = *(const bf16x8*)(qrl + 32);

    if (tid < 64) qn_s[tid] = QN[(size_t)bh * NN + qt * 64 + tid];

    f32x4 Oacc[4];
    float m_st[4], l_st[4];
    #pragma unroll
    for (int r = 0; r < 4; ++r) {
        m_st[r] = -INFINITY; l_st[r] = 0.f;
        Oacc[r] = (f32x4){0.f, 0.f, 0.f, 0.f};
    }

    const int srow = tid >> 2, sch = tid & 3;

    for (int kt = 0; kt <= qt; ++kt) {
        // ---- stage K hi/lo + Vt tile + kn ----
        {
            const unsigned short* kh = Khi + base + ((size_t)(kt * 64 + srow) << 6);
            const unsigned short* kl = Klo + base + ((size_t)(kt * 64 + srow) << 6);
            const unsigned short* vt = Vt  + base + (size_t)srow * NN + kt * 64;
            #pragma unroll
            for (int half = 0; half < 2; ++half) {
                const int col = sch * 8 + half * 32;
                *(uint4*)&Kh_s[srow * LDK + col] = *(const uint4*)(kh + col);
                *(uint4*)&Kl_s[srow * LDK + col] = *(const uint4*)(kl + col);
                *(uint4*)&Vt_s[srow * LDK + col] = *(const uint4*)(vt + col);
            }
            if (tid < 64) kn_s[tid] = KN[(size_t)bh * NN + kt * 64 + tid];
        }
        __syncthreads();

        // ---- S = Q K^T (hi/lo compensated) ----
        f32x4 S[4];
        #pragma unroll
        for (int t = 0; t < 4; ++t) {
            f32x4 acc = (f32x4){0.f, 0.f, 0.f, 0.f};
            #pragma unroll
            for (int c2 = 0; c2 < 2; ++c2) {
                const int off = (t * 16 + lx) * LDK + c2 * 32 + q4 * 8;
                const bf16x8 kh = *(const bf16x8*)&Kh_s[off];
                const bf16x8 kl = *(const bf16x8*)&Kl_s[off];
                const bf16x8 qh = c2 ? qh1 : qh0;
                const bf16x8 ql = c2 ? ql1 : ql0;
                acc = __builtin_amdgcn_mfma_f32_16x16x32_bf16(qh, kh, acc, 0, 0, 0);
                acc = __builtin_amdgcn_mfma_f32_16x16x32_bf16(qh, kl, acc, 0, 0, 0);
                acc = __builtin_amdgcn_mfma_f32_16x16x32_bf16(ql, kh, acc, 0, 0, 0);
            }
            S[t] = acc;
        }

        // ---- hyperbolic distance -> scores, online softmax ----
        float qn_r[4];
        #pragma unroll
        for (int r = 0; r < 4; ++r) qn_r[r] = qn_s[w * 16 + q4 * 4 + r];
        const bool diag = (kt == qt);

        float mrow[4] = {-INFINITY, -INFINITY, -INFINITY, -INFINITY};
        #pragma unroll
        for (int t = 0; t < 4; ++t) {
            const float kn = kn_s[t * 16 + lx];
            #pragma unroll
            for (int r = 0; r < 4; ++r) {
                const float sumn = qn_r[r] + kn;
                float diff = fmaxf(fmaf(-2.f, S[t][r], sumn), 0.f);
                float s = -beta * sqrtf(fmaf(hc, sumn, 1.f) * (diff + 1e-8f));
                const int cc = t * 16 + lx;
                const int rr = w * 16 + q4 * 4 + r;
                if (diag && cc > rr) s = -INFINITY; // causal mask
                S[t][r] = s;
                mrow[r] = fmaxf(mrow[r], s);
            }
        }

        #pragma unroll
        for (int r = 0; r < 4; ++r) {
            float m = mrow[r];
            m = fmaxf(m, __shfl_xor(m, 1));
            m = fmaxf(m, __shfl_xor(m, 2));
            m = fmaxf(m, __shfl_xor(m, 4));
            m = fmaxf(m, __shfl_xor(m, 8));
            const float mn = fmaxf(m_st[r], m);
            const float al = __expf(m_st[r] - mn);
            m_st[r] = mn;
            float rs = 0.f;
            #pragma unroll
            for (int t = 0; t < 4; ++t) {
                const float p = __expf(S[t][r] - mn);
                rs += p;
                P_s[(w * 16 + q4 * 4 + r) * LDK + t * 16 + lx] = f2bf(p);
            }
            rs += __shfl_xor(rs, 1);
            rs += __shfl_xor(rs, 2);
            rs += __shfl_xor(rs, 4);
            rs += __shfl_xor(rs, 8);
            l_st[r] = l_st[r] * al + rs;
            #pragma unroll
            for (int t = 0; t < 4; ++t) Oacc[t][r] *= al;
        }
        __syncthreads();   // P_s visible (wave-local, but keep conservative)

        // ---- O += P V  (A = P from LDS, B = V via Vt rows) ----
        #pragma unroll
        for (int c2 = 0; c2 < 2; ++c2) {
            const bf16x8 pa = *(const bf16x8*)&P_s[(w * 16 + lx) * LDK + c2 * 32 + q4 * 8];
            #pragma unroll
            for (int t = 0; t < 4; ++t) {
                const bf16x8 vb = *(const bf16x8*)&Vt_s[(t * 16 + lx) * LDK + c2 * 32 + q4 * 8];
                Oacc[t] = __builtin_amdgcn_mfma_f32_16x16x32_bf16(pa, vb, Oacc[t], 0, 0, 0);
            }
        }
        __syncthreads();   // protect K/Vt/P before next stage
    }

    // ---- epilogue: normalize, store [B,H,N,64] fp32 ----
    #pragma unroll
    for (int r = 0; r < 4; ++r) {
        const float inv = 1.f / l_st[r];
        const size_t rowoff = base + ((size_t)(qt * 64 + w * 16 + q4 * 4 + r) << 6);
        #pragma unroll
        for (int t = 0; t < 4; ++t)
            AO[rowoff + t * 16 + lx] = Oacc[t][r] * inv;
    }
}

// ---------------------------------------------------------------------------
// Output projection: out = attn_out @ Wo.T (fp32), AO [B,H,N,dh] -> [B,N,D]
// ---------------------------------------------------------------------------
__global__ __launch_bounds__(256, 2)
void out_gemm(const float* __restrict__ AO, const float* __restrict__ Wo,
              float* __restrict__ Out)
{
    const int m0 = blockIdx.x * 64;
    const int n0 = blockIdx.y * 64;

    __shared__ float As[16][68];
    __shared__ float Bs[16][68];

    const int tid = threadIdx.x;
    const int lm  = tid >> 2;
    const int lk4 = (tid & 3) << 2;
    const int tx  = tid & 15;
    const int ty  = tid >> 4;

    float acc[4][4] = {};

    const int mrow = m0 + lm;
    const int b = mrow >> 11;
    const int n = mrow & 2047;

    for (int k0 = 0; k0 < DDIM; k0 += 16) {
        const int e = k0 + lk4;
        float4 xa = *(const float4*)(AO + (((size_t)(b * HH + (e >> 6)) * NN + n) << 6) + (e & 63));
        float4 wb = *(const float4*)(Wo + (size_t)(n0 + lm) * DDIM + k0 + lk4);
        As[lk4+0][lm] = xa.x; As[lk4+1][lm] = xa.y; As[lk4+2][lm] = xa.z; As[lk4+3][lm] = xa.w;
        Bs[lk4+0][lm] = wb.x; Bs[lk4+1][lm] = wb.y; Bs[lk4+2][lm] = wb.z; Bs[lk4+3][lm] = wb.w;
        __syncthreads();
        #pragma unroll
        for (int kk = 0; kk < 16; ++kk) {
            float4 a = *(const float4*)&As[kk][ty << 2];
            float4 b4 = *(const float4*)&Bs[kk][tx << 2];
            float av[4] = {a.x, a.y, a.z, a.w};
            float bv[4] = {b4.x, b4.y, b4.z, b4.w};
            #pragma unroll
            for (int i = 0; i < 4; ++i)
                #pragma unroll
                for (int j = 0; j < 4; ++j)
                    acc[i][j] = fmaf(av[i], bv[j], acc[i][j]);
        }
        __syncthreads();
    }

    #pragma unroll
    for (int i = 0; i < 4; ++i) {
        const int m = m0 + (ty << 2) + i;
        *(float4*)(Out + (size_t)m * DDIM + n0 + (tx << 2)) =
            make_float4(acc[i][0], acc[i][1], acc[i][2], acc[i][3]);
    }
}

// ---------------------------------------------------------------------------
extern "C" void kernel_launch(void* const* d_in, const int* in_sizes, int n_in,
                              void* d_out, int out_size, void* d_ws, size_t ws_size,
                              hipStream_t stream)
{
    const float* x        = (const float*)d_in[0];
    const float* Wq       = (const float*)d_in[1];
    const float* Wk       = (const float*)d_in[2];
    const float* Wv       = (const float*)d_in[3];
    const float* Wo       = (const float*)d_in[4];
    const float* log_c    = (const float*)d_in[5];
    const float* log_beta = (const float*)d_in[6];
    float* out = (float*)d_out;

    const size_t E = (size_t)BB * HH * NN * DH;   // 2,097,152
    float* AO = (float*)d_ws;                      // 8 MB
    unsigned short* Qhi = (unsigned short*)(AO + E);
    unsigned short* Qlo = Qhi + E;
    unsigned short* Khi = Qlo + E;
    unsigned short* Klo = Khi + E;
    unsigned short* Vb  = Klo + E;
    unsigned short* Vtr = Vb + E;
    float* QN = (float*)(Vtr + E);
    float* KN = QN + (size_t)BB * HH * NN;

    proj_gemm  <<<dim3(MTOT / 64, HH, 3), 256, 0, stream>>>(x, Wq, Wk, Wv,
                                                            Qhi, Qlo, Khi, Klo, Vb, QN, KN);
    v_transpose<<<dim3(512), 256, 0, stream>>>(Vb, Vtr);
    attn_mfma  <<<dim3(512), 256, 0, stream>>>(Qhi, Qlo, Khi, Klo, Vtr, QN, KN,
                                               log_c, log_beta, AO);
    out_gemm   <<<dim3(MTOT / 64, DDIM / 64), 256, 0, stream>>>(AO, Wo, out);
}

// Round 5
// 230.174 us; speedup vs baseline: 1.7583x; 1.3829x over previous
//
#include <hip/hip_runtime.h>
#include <math.h>

#define BB   2
#define NN   2048
#define DDIM 512
#define HH   8
#define DH   64
#define MTOT (BB*NN)      // 4096
#define LDK  72           // ushort stride for attn 64-wide bf16 LDS rows
#define EE   (BB*HH*NN*DH)   // 2,097,152 elems per Q/K/V-like array
#define WN   (DDIM*DDIM)     // 262,144 elems per weight

typedef __attribute__((ext_vector_type(8))) short bf16x8;   // 8 bf16 = 4 VGPRs
typedef __attribute__((ext_vector_type(4))) float f32x4;

__device__ __forceinline__ float softplus_f(float x) {
    return x > 20.f ? x : log1pf(expf(x));
}
__device__ __forceinline__ unsigned short f2bf(float x) {   // round-to-nearest-even
    union { float f; unsigned u; } v; v.f = x;
    unsigned r = v.u + 0x7fffu + ((v.u >> 16) & 1u);
    return (unsigned short)(r >> 16);
}
__device__ __forceinline__ float bf2f(unsigned short h) {
    union { unsigned u; float f; } v; v.u = ((unsigned)h) << 16; return v.f;
}

// ---------------------------------------------------------------------------
// Split fp32 -> bf16 hi/lo pairs. blockIdx.y selects {x, Wq, Wk, Wv, Wo}.
// ---------------------------------------------------------------------------
__global__ __launch_bounds__(256)
void split_hl(const float* __restrict__ x,  const float* __restrict__ Wq,
              const float* __restrict__ Wk, const float* __restrict__ Wv,
              const float* __restrict__ Wo,
              unsigned short* __restrict__ xh,  unsigned short* __restrict__ xl,
              unsigned short* __restrict__ wqh, unsigned short* __restrict__ wql,
              unsigned short* __restrict__ wkh, unsigned short* __restrict__ wkl,
              unsigned short* __restrict__ wvh, unsigned short* __restrict__ wvl,
              unsigned short* __restrict__ woh, unsigned short* __restrict__ wol)
{
    const float* src; unsigned short *dh, *dl; int nq;
    switch (blockIdx.y) {
        case 0:  src = x;  dh = xh;  dl = xl;  nq = EE / 4; break;
        case 1:  src = Wq; dh = wqh; dl = wql; nq = WN / 4; break;
        case 2:  src = Wk; dh = wkh; dl = wkl; nq = WN / 4; break;
        case 3:  src = Wv; dh = wvh; dl = wvl; nq = WN / 4; break;
        default: src = Wo; dh = woh; dl = wol; nq = WN / 4; break;
    }
    for (int i = blockIdx.x * 256 + threadIdx.x; i < nq; i += gridDim.x * 256) {
        float4 v = *(const float4*)(src + 4 * (size_t)i);
        ushort4 h, l;
        h.x = f2bf(v.x); l.x = f2bf(v.x - bf2f(h.x));
        h.y = f2bf(v.y); l.y = f2bf(v.y - bf2f(h.y));
        h.z = f2bf(v.z); l.z = f2bf(v.z - bf2f(h.z));
        h.w = f2bf(v.w); l.w = f2bf(v.w - bf2f(h.w));
        *(ushort4*)(dh + 4 * (size_t)i) = h;
        *(ushort4*)(dl + 4 * (size_t)i) = l;
    }
}

// ---------------------------------------------------------------------------
// Unified hi/lo-compensated bf16 MFMA GEMM: C[m][j] = sum_k A[m][k] * W[j][k].
// mode 0/1/2 (proj, blockIdx.z): A = x (plain rows), epilogue -> Q/K hi+lo
// splits or V bf16 in [B,H,N,dh]. mode 3 (is_out): A = AO (BHND gather),
// epilogue -> fp32 out. 128x128 tile, BK=32, 2x2 waves of 4x4 16x16x32 MFMAs.
// LDS layout [kq][128][8] ushort: contiguous 16B lines, write-conflict-free.
// ---------------------------------------------------------------------------
__global__ __launch_bounds__(256)
void mm_mfma(const unsigned short* __restrict__ Ahg, const unsigned short* __restrict__ Alg,
             const unsigned short* __restrict__ W0h, const unsigned short* __restrict__ W0l,
             const unsigned short* __restrict__ W1h, const unsigned short* __restrict__ W1l,
             const unsigned short* __restrict__ W2h, const unsigned short* __restrict__ W2l,
             const int is_out,
             unsigned short* __restrict__ Qhi, unsigned short* __restrict__ Qlo,
             unsigned short* __restrict__ Khi, unsigned short* __restrict__ Klo,
             unsigned short* __restrict__ Vb, float* __restrict__ Outp)
{
    const int mode = is_out ? 3 : (int)blockIdx.z;
    const unsigned short* Wh = (mode == 1) ? W1h : ((mode == 2) ? W2h : W0h);
    const unsigned short* Wl = (mode == 1) ? W1l : ((mode == 2) ? W2l : W0l);
    const int m0 = blockIdx.x * 128, n0 = blockIdx.y * 128;

    __shared__ unsigned short Ah_s[4 * 128 * 8];
    __shared__ unsigned short Al_s[4 * 128 * 8];
    __shared__ unsigned short Bh_s[4 * 128 * 8];
    __shared__ unsigned short Bl_s[4 * 128 * 8];

    const int tid  = threadIdx.x;
    const int lane = tid & 63, lx = lane & 15, q4 = lane >> 4;
    const int w = tid >> 6, wm = w & 1, wn = w >> 1;
    const int srow = tid & 127, skh = tid >> 7;      // staging: row, k-half

    f32x4 acc[4][4];
    #pragma unroll
    for (int mt = 0; mt < 4; ++mt)
        #pragma unroll
        for (int nt = 0; nt < 4; ++nt)
            acc[mt][nt] = (f32x4){0.f, 0.f, 0.f, 0.f};

    const int am = m0 + srow;
    const int ab = am >> 11, an = am & 2047;
    const size_t brow = (size_t)(n0 + srow) * DDIM;

    // preload k0 = 0
    uint4 ra0, ra1, ra2, ra3, rb0, rb1, rb2, rb3;
    {
        const int e = skh * 16;
        size_t aoff = (mode == 3)
            ? ((((size_t)(ab * HH + (e >> 6)) * NN + an) << 6) + (e & 63))
            : ((size_t)am * DDIM + e);
        ra0 = *(const uint4*)(Ahg + aoff);     ra1 = *(const uint4*)(Ahg + aoff + 8);
        ra2 = *(const uint4*)(Alg + aoff);     ra3 = *(const uint4*)(Alg + aoff + 8);
        rb0 = *(const uint4*)(Wh + brow + e);  rb1 = *(const uint4*)(Wh + brow + e + 8);
        rb2 = *(const uint4*)(Wl + brow + e);  rb3 = *(const uint4*)(Wl + brow + e + 8);
    }

    for (int k0 = 0; k0 < DDIM; k0 += 32) {
        __syncthreads();    // previous compute done (safe to overwrite LDS)
        const int kq = skh * 2;
        *(uint4*)&Ah_s[((kq + 0) * 128 + srow) * 8] = ra0;
        *(uint4*)&Ah_s[((kq + 1) * 128 + srow) * 8] = ra1;
        *(uint4*)&Al_s[((kq + 0) * 128 + srow) * 8] = ra2;
        *(uint4*)&Al_s[((kq + 1) * 128 + srow) * 8] = ra3;
        *(uint4*)&Bh_s[((kq + 0) * 128 + srow) * 8] = rb0;
        *(uint4*)&Bh_s[((kq + 1) * 128 + srow) * 8] = rb1;
        *(uint4*)&Bl_s[((kq + 0) * 128 + srow) * 8] = rb2;
        *(uint4*)&Bl_s[((kq + 1) * 128 + srow) * 8] = rb3;
        __syncthreads();    // staged tile visible

        if (k0 + 32 < DDIM) {   // prefetch next K-slice (overlaps with MFMAs)
            const int e = k0 + 32 + skh * 16;
            size_t aoff = (mode == 3)
                ? ((((size_t)(ab * HH + (e >> 6)) * NN + an) << 6) + (e & 63))
                : ((size_t)am * DDIM + e);
            ra0 = *(const uint4*)(Ahg + aoff);     ra1 = *(const uint4*)(Ahg + aoff + 8);
            ra2 = *(const uint4*)(Alg + aoff);     ra3 = *(const uint4*)(Alg + aoff + 8);
            rb0 = *(const uint4*)(Wh + brow + e);  rb1 = *(const uint4*)(Wh + brow + e + 8);
            rb2 = *(const uint4*)(Wl + brow + e);  rb3 = *(const uint4*)(Wl + brow + e + 8);
        }

        bf16x8 fah[4], fal[4], fbh[4], fbl[4];
        #pragma unroll
        for (int t = 0; t < 4; ++t) {
            fah[t] = *(const bf16x8*)&Ah_s[(q4 * 128 + wm * 64 + t * 16 + lx) * 8];
            fal[t] = *(const bf16x8*)&Al_s[(q4 * 128 + wm * 64 + t * 16 + lx) * 8];
            fbh[t] = *(const bf16x8*)&Bh_s[(q4 * 128 + wn * 64 + t * 16 + lx) * 8];
            fbl[t] = *(const bf16x8*)&Bl_s[(q4 * 128 + wn * 64 + t * 16 + lx) * 8];
        }
        #pragma unroll
        for (int mt = 0; mt < 4; ++mt)
            #pragma unroll
            for (int nt = 0; nt < 4; ++nt) {
                acc[mt][nt] = __builtin_amdgcn_mfma_f32_16x16x32_bf16(fah[mt], fbh[nt], acc[mt][nt], 0, 0, 0);
                acc[mt][nt] = __builtin_amdgcn_mfma_f32_16x16x32_bf16(fah[mt], fbl[nt], acc[mt][nt], 0, 0, 0);
                acc[mt][nt] = __builtin_amdgcn_mfma_f32_16x16x32_bf16(fal[mt], fbh[nt], acc[mt][nt], 0, 0, 0);
            }
    }

    // epilogue: C row m = q4*4+reg, col j = lx (verified mapping)
    #pragma unroll
    for (int mt = 0; mt < 4; ++mt) {
        #pragma unroll
        for (int r = 0; r < 4; ++r) {
            const int m = m0 + wm * 64 + mt * 16 + q4 * 4 + r;
            const int b = m >> 11, n2 = m & 2047;
            #pragma unroll
            for (int nt = 0; nt < 4; ++nt) {
                const int j = n0 + wn * 64 + nt * 16 + lx;
                const float v = acc[mt][nt][r];
                if (mode == 3) {
                    Outp[(size_t)m * DDIM + j] = v;
                } else {
                    const size_t idx = (((size_t)(b * HH + (j >> 6)) * NN + n2) << 6) + (j & 63);
                    if (mode == 2) {
                        Vb[idx] = f2bf(v);
                    } else {
                        const unsigned short h = f2bf(v);
                        const unsigned short l = f2bf(v - bf2f(h));
                        if (mode == 0) { Qhi[idx] = h; Qlo[idx] = l; }
                        else           { Khi[idx] = h; Klo[idx] = l; }
                    }
                }
            }
        }
    }
}

// ---------------------------------------------------------------------------
// Row norms from hi/lo pairs: QN[row] = sum((hi+lo)^2) — exactly consistent
// with the values attn's compensated QK^T effectively uses.
// ---------------------------------------------------------------------------
__global__ __launch_bounds__(256)
void norms2(const unsigned short* __restrict__ Qh, const unsigned short* __restrict__ Ql,
            const unsigned short* __restrict__ Kh, const unsigned short* __restrict__ Kl,
            float* __restrict__ QN, float* __restrict__ KN)
{
    const int row = blockIdx.x * 64 + (threadIdx.x >> 2);
    const int seg = (threadIdx.x & 3) << 4;
    const unsigned short* ph = ((blockIdx.y == 0) ? Qh : Kh) + ((size_t)row << 6) + seg;
    const unsigned short* pl = ((blockIdx.y == 0) ? Ql : Kl) + ((size_t)row << 6) + seg;
    float s = 0.f;
    #pragma unroll
    for (int t = 0; t < 16; t += 8) {
        union { uint4 v; unsigned short u[8]; } h8, l8;
        h8.v = *(const uint4*)(ph + t);
        l8.v = *(const uint4*)(pl + t);
        #pragma unroll
        for (int j = 0; j < 8; ++j) {
            const float v = bf2f(h8.u[j]) + bf2f(l8.u[j]);
            s += v * v;
        }
    }
    s += __shfl_xor(s, 1);
    s += __shfl_xor(s, 2);
    if ((threadIdx.x & 3) == 0) ((blockIdx.y == 0) ? QN : KN)[row] = s;
}

// ---------------------------------------------------------------------------
// V transpose: Vb [B,H,N,64] bf16 -> Vt [B,H,64,N] bf16 (for MFMA B-fragments)
// ---------------------------------------------------------------------------
__global__ __launch_bounds__(256)
void v_transpose(const unsigned short* __restrict__ Vb, unsigned short* __restrict__ Vt)
{
    __shared__ unsigned short T[64 * LDK];
    const int id = blockIdx.x;          // 512 = 16 bh * 32 n-tiles
    const int bh = id >> 5, nt = id & 31;
    const size_t ibase = (((size_t)bh * NN + nt * 64) << 6);
    const int row = threadIdx.x >> 2, ch = threadIdx.x & 3;

    #pragma unroll
    for (int half = 0; half < 2; ++half) {
        const int col = ch * 8 + half * 32;
        *(uint4*)&T[row * LDK + col] = *(const uint4*)(Vb + ibase + (row << 6) + col);
    }
    __syncthreads();

    const size_t obase = (size_t)bh * 64 * NN;
    #pragma unroll
    for (int half = 0; half < 2; ++half) {
        const int col = ch * 8 + half * 32;
        union { unsigned short u[8]; uint4 v; } tmp;
        #pragma unroll
        for (int j = 0; j < 8; ++j) tmp.u[j] = T[(col + j) * LDK + row];
        *(uint4*)(Vt + obase + (size_t)row * NN + nt * 64 + col) = tmp.v;
    }
}

// ---------------------------------------------------------------------------
// MFMA flash attention (causal hyperbolic). Round-5: VGPR prefetch of next
// K/V tile (global latency hidden behind compute), post-softmax barrier
// removed (P_s is wave-local: wave w writes rows [16w,16w+16) and only reads
// those back; same-wave DS ops are pipe-ordered), epilogue emits AO hi/lo.
// ---------------------------------------------------------------------------
__global__ __launch_bounds__(256, 2)
void attn_mfma(const unsigned short* __restrict__ Qhi, const unsigned short* __restrict__ Qlo,
               const unsigned short* __restrict__ Khi, const unsigned short* __restrict__ Klo,
               const unsigned short* __restrict__ Vt,
               const float* __restrict__ QN, const float* __restrict__ KN,
               const float* __restrict__ pLC, const float* __restrict__ pLB,
               unsigned short* __restrict__ AOh, unsigned short* __restrict__ AOl)
{
    __shared__ unsigned short Kh_s[64 * LDK];
    __shared__ unsigned short Kl_s[64 * LDK];
    __shared__ unsigned short Vt_s[64 * LDK];
    __shared__ unsigned short P_s [64 * LDK];
    __shared__ float kn_s[64];
    __shared__ float qn_s[64];

    const int id = blockIdx.x;
    int bh, qt;
    if (id < 256) { qt = id >> 3;                 bh = id & 7; }
    else          { int t2 = id - 256; qt = 31 - (t2 >> 3); bh = 8 + (t2 & 7); }

    const int tid  = threadIdx.x;
    const int w    = tid >> 6;
    const int lane = tid & 63;
    const int lx   = lane & 15;
    const int q4   = lane >> 4;

    const float hc   = softplus_f(pLC[0]);
    const float beta = softplus_f(pLB[0]) + 0.5f;

    const size_t base = ((size_t)bh * NN) << 6;

    // Q fragments (A-layout: m=lx, k=q4*8+j), held in registers
    const unsigned short* qrh = Qhi + base + ((size_t)(qt * 64 + w * 16 + lx) << 6) + q4 * 8;
    const unsigned short* qrl = Qlo + base + ((size_t)(qt * 64 + w * 16 + lx) << 6) + q4 * 8;
    const bf16x8 qh0 = *(const bf16x8*)(qrh);
    const bf16x8 qh1 = *(const bf16x8*)(qrh + 32);
    const bf16x8 ql0 = *(const bf16x8*)(qrl);
    const bf16x8 ql1 = *(const bf16x8*)(qrl + 32);

    if (tid < 64) qn_s[tid] = QN[(size_t)bh * NN + qt * 64 + tid];

    f32x4 Oacc[4];
    float m_st[4], l_st[4];
    #pragma unroll
    for (int r = 0; r < 4; ++r) {
        m_st[r] = -INFINITY; l_st[r] = 0.f;
        Oacc[r] = (f32x4){0.f, 0.f, 0.f, 0.f};
    }

    const int srow = tid >> 2, sch = tid & 3;

    // prefetch tile kt = 0
    uint4 pKh0, pKh1, pKl0, pKl1, pVt0, pVt1; float pkn = 0.f;
    {
        const unsigned short* kh = Khi + base + ((size_t)srow << 6);
        const unsigned short* kl = Klo + base + ((size_t)srow << 6);
        const unsigned short* vt = Vt  + base + (size_t)srow * NN;
        pKh0 = *(const uint4*)(kh + sch * 8);  pKh1 = *(const uint4*)(kh + sch * 8 + 32);
        pKl0 = *(const uint4*)(kl + sch * 8);  pKl1 = *(const uint4*)(kl + sch * 8 + 32);
        pVt0 = *(const uint4*)(vt + sch * 8);  pVt1 = *(const uint4*)(vt + sch * 8 + 32);
        if (tid < 64) pkn = KN[(size_t)bh * NN + tid];
    }

    __syncthreads();   // qn_s visible

    for (int kt = 0; kt <= qt; ++kt) {
        // ---- commit prefetched tile to LDS ----
        *(uint4*)&Kh_s[srow * LDK + sch * 8]      = pKh0;
        *(uint4*)&Kh_s[srow * LDK + sch * 8 + 32] = pKh1;
        *(uint4*)&Kl_s[srow * LDK + sch * 8]      = pKl0;
        *(uint4*)&Kl_s[srow * LDK + sch * 8 + 32] = pKl1;
        *(uint4*)&Vt_s[srow * LDK + sch * 8]      = pVt0;
        *(uint4*)&Vt_s[srow * LDK + sch * 8 + 32] = pVt1;
        if (tid < 64) kn_s[tid] = pkn;
        __syncthreads();

        // ---- prefetch tile kt+1 (in flight during compute) ----
        if (kt < qt) {
            const unsigned short* kh = Khi + base + ((size_t)((kt + 1) * 64 + srow) << 6);
            const unsigned short* kl = Klo + base + ((size_t)((kt + 1) * 64 + srow) << 6);
            const unsigned short* vt = Vt  + base + (size_t)srow * NN + (kt + 1) * 64;
            pKh0 = *(const uint4*)(kh + sch * 8);  pKh1 = *(const uint4*)(kh + sch * 8 + 32);
            pKl0 = *(const uint4*)(kl + sch * 8);  pKl1 = *(const uint4*)(kl + sch * 8 + 32);
            pVt0 = *(const uint4*)(vt + sch * 8);  pVt1 = *(const uint4*)(vt + sch * 8 + 32);
            if (tid < 64) pkn = KN[(size_t)bh * NN + (kt + 1) * 64 + tid];
        }

        // ---- S = Q K^T (hi/lo compensated) ----
        f32x4 S[4];
        #pragma unroll
        for (int t = 0; t < 4; ++t) {
            f32x4 acc = (f32x4){0.f, 0.f, 0.f, 0.f};
            #pragma unroll
            for (int c2 = 0; c2 < 2; ++c2) {
                const int off = (t * 16 + lx) * LDK + c2 * 32 + q4 * 8;
                const bf16x8 kh = *(const bf16x8*)&Kh_s[off];
                const bf16x8 kl = *(const bf16x8*)&Kl_s[off];
                const bf16x8 qh = c2 ? qh1 : qh0;
                const bf16x8 ql = c2 ? ql1 : ql0;
                acc = __builtin_amdgcn_mfma_f32_16x16x32_bf16(qh, kh, acc, 0, 0, 0);
                acc = __builtin_amdgcn_mfma_f32_16x16x32_bf16(qh, kl, acc, 0, 0, 0);
                acc = __builtin_amdgcn_mfma_f32_16x16x32_bf16(ql, kh, acc, 0, 0, 0);
            }
            S[t] = acc;
        }

        // ---- hyperbolic distance -> scores, online softmax ----
        float qn_r[4];
        #pragma unroll
        for (int r = 0; r < 4; ++r) qn_r[r] = qn_s[w * 16 + q4 * 4 + r];
        const bool diag = (kt == qt);

        float mrow[4] = {-INFINITY, -INFINITY, -INFINITY, -INFINITY};
        #pragma unroll
        for (int t = 0; t < 4; ++t) {
            const float kn = kn_s[t * 16 + lx];
            #pragma unroll
            for (int r = 0; r < 4; ++r) {
                const float sumn = qn_r[r] + kn;
                float diff = fmaxf(fmaf(-2.f, S[t][r], sumn), 0.f);
                float s = -beta * sqrtf(fmaf(hc, sumn, 1.f) * (diff + 1e-8f));
                const int cc = t * 16 + lx;
                const int rr = w * 16 + q4 * 4 + r;
                if (diag && cc > rr) s = -INFINITY;
                S[t][r] = s;
                mrow[r] = fmaxf(mrow[r], s);
            }
        }

        #pragma unroll
        for (int r = 0; r < 4; ++r) {
            float m = mrow[r];
            m = fmaxf(m, __shfl_xor(m, 1));
            m = fmaxf(m, __shfl_xor(m, 2));
            m = fmaxf(m, __shfl_xor(m, 4));
            m = fmaxf(m, __shfl_xor(m, 8));
            const float mn = fmaxf(m_st[r], m);
            const float al = __expf(m_st[r] - mn);
            m_st[r] = mn;
            float rs = 0.f;
            #pragma unroll
            for (int t = 0; t < 4; ++t) {
                const float p = __expf(S[t][r] - mn);
                rs += p;
                P_s[(w * 16 + q4 * 4 + r) * LDK + t * 16 + lx] = f2bf(p);
            }
            rs += __shfl_xor(rs, 1);
            rs += __shfl_xor(rs, 2);
            rs += __shfl_xor(rs, 4);
            rs += __shfl_xor(rs, 8);
            l_st[r] = l_st[r] * al + rs;
            #pragma unroll
            for (int t = 0; t < 4; ++t) Oacc[t][r] *= al;
        }

        // P_s is wave-local (rows [16w,16w+16) written and read by wave w);
        // same-wave DS ops are pipe-ordered — no __syncthreads needed.
        __builtin_amdgcn_wave_barrier();

        // ---- O += P V ----
        #pragma unroll
        for (int c2 = 0; c2 < 2; ++c2) {
            const bf16x8 pa = *(const bf16x8*)&P_s[(w * 16 + lx) * LDK + c2 * 32 + q4 * 8];
            #pragma unroll
            for (int t = 0; t < 4; ++t) {
                const bf16x8 vb = *(const bf16x8*)&Vt_s[(t * 16 + lx) * LDK + c2 * 32 + q4 * 8];
                Oacc[t] = __builtin_amdgcn_mfma_f32_16x16x32_bf16(pa, vb, Oacc[t], 0, 0, 0);
            }
        }
        __syncthreads();   // all waves done reading K/Vt before next commit
    }

    // ---- epilogue: normalize, store AO as bf16 hi/lo in [B,H,N,64] ----
    #pragma unroll
    for (int r = 0; r < 4; ++r) {
        const float inv = 1.f / l_st[r];
        const size_t rowoff = base + ((size_t)(qt * 64 + w * 16 + q4 * 4 + r) << 6);
        #pragma unroll
        for (int t = 0; t < 4; ++t) {
            const float o = Oacc[t][r] * inv;
            const unsigned short h = f2bf(o);
            const unsigned short l = f2bf(o - bf2f(h));
            AOh[rowoff + t * 16 + lx] = h;
            AOl[rowoff + t * 16 + lx] = l;
        }
    }
}

// ---------------------------------------------------------------------------
extern "C" void kernel_launch(void* const* d_in, const int* in_sizes, int n_in,
                              void* d_out, int out_size, void* d_ws, size_t ws_size,
                              hipStream_t stream)
{
    const float* x        = (const float*)d_in[0];
    const float* Wq       = (const float*)d_in[1];
    const float* Wk       = (const float*)d_in[2];
    const float* Wv       = (const float*)d_in[3];
    const float* Wo       = (const float*)d_in[4];
    const float* log_c    = (const float*)d_in[5];
    const float* log_beta = (const float*)d_in[6];
    float* out = (float*)d_out;

    unsigned short* p = (unsigned short*)d_ws;
    unsigned short* xh  = p;            p += EE;
    unsigned short* xl  = p;            p += EE;
    unsigned short* wqh = p;            p += WN;
    unsigned short* wql = p;            p += WN;
    unsigned short* wkh = p;            p += WN;
    unsigned short* wkl = p;            p += WN;
    unsigned short* wvh = p;            p += WN;
    unsigned short* wvl = p;            p += WN;
    unsigned short* woh = p;            p += WN;
    unsigned short* wol = p;            p += WN;
    unsigned short* Qhi = p;            p += EE;
    unsigned short* Qlo = p;            p += EE;
    unsigned short* Khi = p;            p += EE;
    unsigned short* Klo = p;            p += EE;
    unsigned short* Vb  = p;            p += EE;
    unsigned short* Vtr = p;            p += EE;
    unsigned short* AOh = p;            p += EE;
    unsigned short* AOl = p;            p += EE;
    float* QN = (float*)p;
    float* KN = QN + (size_t)BB * HH * NN;

    split_hl   <<<dim3(256, 5), 256, 0, stream>>>(x, Wq, Wk, Wv, Wo,
                                                  xh, xl, wqh, wql, wkh, wkl, wvh, wvl, woh, wol);
    mm_mfma    <<<dim3(MTOT / 128, 4, 3), 256, 0, stream>>>(xh, xl,
                                                  wqh, wql, wkh, wkl, wvh, wvl, 0,
                                                  Qhi, Qlo, Khi, Klo, Vb, nullptr);
    norms2     <<<dim3((BB * HH * NN) / 64, 2), 256, 0, stream>>>(Qhi, Qlo, Khi, Klo, QN, KN);
    v_transpose<<<dim3(512), 256, 0, stream>>>(Vb, Vtr);
    attn_mfma  <<<dim3(512), 256, 0, stream>>>(Qhi, Qlo, Khi, Klo, Vtr, QN, KN,
                                               log_c, log_beta, AOh, AOl);
    mm_mfma    <<<dim3(MTOT / 128, 4, 1), 256, 0, stream>>>(AOh, AOl,
                                                  woh, wol, nullptr, nullptr, nullptr, nullptr, 1,
                                                  nullptr, nullptr, nullptr, nullptr, nullptr, out);
}

// Round 6
// 217.850 us; speedup vs baseline: 1.8578x; 1.0566x over previous
//
#include <hip/hip_runtime.h>
#include <math.h>

#define BB   2
#define NN   2048
#define DDIM 512
#define HH   8
#define DH   64
#define MTOT (BB*NN)      // 4096
#define LDK  72           // ushort stride for attn 64-wide bf16 LDS rows
#define EE   (BB*HH*NN*DH)   // 2,097,152 elems per Q/K/V-like array
#define WN   (DDIM*DDIM)     // 262,144 elems per weight
#define NSLOT (BB*HH*32*4)   // 2048 partial slots (bh x qt x <=4 chunks)

typedef __attribute__((ext_vector_type(8))) short bf16x8;   // 8 bf16 = 4 VGPRs
typedef __attribute__((ext_vector_type(4))) float f32x4;

__device__ __forceinline__ float softplus_f(float x) {
    return x > 20.f ? x : log1pf(expf(x));
}
__device__ __forceinline__ unsigned short f2bf(float x) {   // round-to-nearest-even
    union { float f; unsigned u; } v; v.f = x;
    unsigned r = v.u + 0x7fffu + ((v.u >> 16) & 1u);
    return (unsigned short)(r >> 16);
}
__device__ __forceinline__ float bf2f(unsigned short h) {
    union { unsigned u; float f; } v; v.u = ((unsigned)h) << 16; return v.f;
}

// ---------------------------------------------------------------------------
// Split fp32 -> bf16 hi/lo pairs. blockIdx.y selects {x, Wq, Wk, Wv, Wo}.
// ---------------------------------------------------------------------------
__global__ __launch_bounds__(256)
void split_hl(const float* __restrict__ x,  const float* __restrict__ Wq,
              const float* __restrict__ Wk, const float* __restrict__ Wv,
              const float* __restrict__ Wo,
              unsigned short* __restrict__ xh,  unsigned short* __restrict__ xl,
              unsigned short* __restrict__ wqh, unsigned short* __restrict__ wql,
              unsigned short* __restrict__ wkh, unsigned short* __restrict__ wkl,
              unsigned short* __restrict__ wvh, unsigned short* __restrict__ wvl,
              unsigned short* __restrict__ woh, unsigned short* __restrict__ wol)
{
    const float* src; unsigned short *dh, *dl; int nq;
    switch (blockIdx.y) {
        case 0:  src = x;  dh = xh;  dl = xl;  nq = EE / 4; break;
        case 1:  src = Wq; dh = wqh; dl = wql; nq = WN / 4; break;
        case 2:  src = Wk; dh = wkh; dl = wkl; nq = WN / 4; break;
        case 3:  src = Wv; dh = wvh; dl = wvl; nq = WN / 4; break;
        default: src = Wo; dh = woh; dl = wol; nq = WN / 4; break;
    }
    for (int i = blockIdx.x * 256 + threadIdx.x; i < nq; i += gridDim.x * 256) {
        float4 v = *(const float4*)(src + 4 * (size_t)i);
        ushort4 h, l;
        h.x = f2bf(v.x); l.x = f2bf(v.x - bf2f(h.x));
        h.y = f2bf(v.y); l.y = f2bf(v.y - bf2f(h.y));
        h.z = f2bf(v.z); l.z = f2bf(v.z - bf2f(h.z));
        h.w = f2bf(v.w); l.w = f2bf(v.w - bf2f(h.w));
        *(ushort4*)(dh + 4 * (size_t)i) = h;
        *(ushort4*)(dl + 4 * (size_t)i) = l;
    }
}

// ---------------------------------------------------------------------------
// Unified hi/lo-compensated bf16 MFMA GEMM: C[m][j] = sum_k A[m][k] * W[j][k].
// mode 0/1/2 (proj): epilogue -> Q/K hi+lo (+ fp32 row norms, fused) or V.
// mode 3 (is_out): A = AO (BHND gather), epilogue -> fp32 out.
// 128x128 tile, BK=32, 2x2 waves of 4x4 16x16x32 MFMAs, register prefetch.
// ---------------------------------------------------------------------------
__global__ __launch_bounds__(256)
void mm_mfma(const unsigned short* __restrict__ Ahg, const unsigned short* __restrict__ Alg,
             const unsigned short* __restrict__ W0h, const unsigned short* __restrict__ W0l,
             const unsigned short* __restrict__ W1h, const unsigned short* __restrict__ W1l,
             const unsigned short* __restrict__ W2h, const unsigned short* __restrict__ W2l,
             const int is_out,
             unsigned short* __restrict__ Qhi, unsigned short* __restrict__ Qlo,
             unsigned short* __restrict__ Khi, unsigned short* __restrict__ Klo,
             unsigned short* __restrict__ Vb, float* __restrict__ Outp,
             float* __restrict__ QN, float* __restrict__ KN)
{
    const int mode = is_out ? 3 : (int)blockIdx.z;
    const unsigned short* Wh = (mode == 1) ? W1h : ((mode == 2) ? W2h : W0h);
    const unsigned short* Wl = (mode == 1) ? W1l : ((mode == 2) ? W2l : W0l);
    const int m0 = blockIdx.x * 128, n0 = blockIdx.y * 128;

    __shared__ unsigned short Ah_s[4 * 128 * 8];
    __shared__ unsigned short Al_s[4 * 128 * 8];
    __shared__ unsigned short Bh_s[4 * 128 * 8];
    __shared__ unsigned short Bl_s[4 * 128 * 8];

    const int tid  = threadIdx.x;
    const int lane = tid & 63, lx = lane & 15, q4 = lane >> 4;
    const int w = tid >> 6, wm = w & 1, wn = w >> 1;
    const int srow = tid & 127, skh = tid >> 7;      // staging: row, k-half

    f32x4 acc[4][4];
    #pragma unroll
    for (int mt = 0; mt < 4; ++mt)
        #pragma unroll
        for (int nt = 0; nt < 4; ++nt)
            acc[mt][nt] = (f32x4){0.f, 0.f, 0.f, 0.f};

    const int am = m0 + srow;
    const int ab = am >> 11, an = am & 2047;
    const size_t brow = (size_t)(n0 + srow) * DDIM;

    // preload k0 = 0
    uint4 ra0, ra1, ra2, ra3, rb0, rb1, rb2, rb3;
    {
        const int e = skh * 16;
        size_t aoff = (mode == 3)
            ? ((((size_t)(ab * HH + (e >> 6)) * NN + an) << 6) + (e & 63))
            : ((size_t)am * DDIM + e);
        ra0 = *(const uint4*)(Ahg + aoff);     ra1 = *(const uint4*)(Ahg + aoff + 8);
        ra2 = *(const uint4*)(Alg + aoff);     ra3 = *(const uint4*)(Alg + aoff + 8);
        rb0 = *(const uint4*)(Wh + brow + e);  rb1 = *(const uint4*)(Wh + brow + e + 8);
        rb2 = *(const uint4*)(Wl + brow + e);  rb3 = *(const uint4*)(Wl + brow + e + 8);
    }

    for (int k0 = 0; k0 < DDIM; k0 += 32) {
        __syncthreads();    // previous compute done (safe to overwrite LDS)
        const int kq = skh * 2;
        *(uint4*)&Ah_s[((kq + 0) * 128 + srow) * 8] = ra0;
        *(uint4*)&Ah_s[((kq + 1) * 128 + srow) * 8] = ra1;
        *(uint4*)&Al_s[((kq + 0) * 128 + srow) * 8] = ra2;
        *(uint4*)&Al_s[((kq + 1) * 128 + srow) * 8] = ra3;
        *(uint4*)&Bh_s[((kq + 0) * 128 + srow) * 8] = rb0;
        *(uint4*)&Bh_s[((kq + 1) * 128 + srow) * 8] = rb1;
        *(uint4*)&Bl_s[((kq + 0) * 128 + srow) * 8] = rb2;
        *(uint4*)&Bl_s[((kq + 1) * 128 + srow) * 8] = rb3;
        __syncthreads();    // staged tile visible

        if (k0 + 32 < DDIM) {   // prefetch next K-slice (overlaps with MFMAs)
            const int e = k0 + 32 + skh * 16;
            size_t aoff = (mode == 3)
                ? ((((size_t)(ab * HH + (e >> 6)) * NN + an) << 6) + (e & 63))
                : ((size_t)am * DDIM + e);
            ra0 = *(const uint4*)(Ahg + aoff);     ra1 = *(const uint4*)(Ahg + aoff + 8);
            ra2 = *(const uint4*)(Alg + aoff);     ra3 = *(const uint4*)(Alg + aoff + 8);
            rb0 = *(const uint4*)(Wh + brow + e);  rb1 = *(const uint4*)(Wh + brow + e + 8);
            rb2 = *(const uint4*)(Wl + brow + e);  rb3 = *(const uint4*)(Wl + brow + e + 8);
        }

        bf16x8 fah[4], fal[4], fbh[4], fbl[4];
        #pragma unroll
        for (int t = 0; t < 4; ++t) {
            fah[t] = *(const bf16x8*)&Ah_s[(q4 * 128 + wm * 64 + t * 16 + lx) * 8];
            fal[t] = *(const bf16x8*)&Al_s[(q4 * 128 + wm * 64 + t * 16 + lx) * 8];
            fbh[t] = *(const bf16x8*)&Bh_s[(q4 * 128 + wn * 64 + t * 16 + lx) * 8];
            fbl[t] = *(const bf16x8*)&Bl_s[(q4 * 128 + wn * 64 + t * 16 + lx) * 8];
        }
        #pragma unroll
        for (int mt = 0; mt < 4; ++mt)
            #pragma unroll
            for (int nt = 0; nt < 4; ++nt) {
                acc[mt][nt] = __builtin_amdgcn_mfma_f32_16x16x32_bf16(fah[mt], fbh[nt], acc[mt][nt], 0, 0, 0);
                acc[mt][nt] = __builtin_amdgcn_mfma_f32_16x16x32_bf16(fah[mt], fbl[nt], acc[mt][nt], 0, 0, 0);
                acc[mt][nt] = __builtin_amdgcn_mfma_f32_16x16x32_bf16(fal[mt], fbh[nt], acc[mt][nt], 0, 0, 0);
            }
    }

    // ---- fused row norms (modes 0/1): row m's head = this wave's wn-half ----
    if (mode == 0 || mode == 1) {
        float* Np = (mode == 0) ? QN : KN;
        const int head = (n0 + wn * 64) >> 6;
        #pragma unroll
        for (int mt = 0; mt < 4; ++mt)
            #pragma unroll
            for (int r = 0; r < 4; ++r) {
                float s = 0.f;
                #pragma unroll
                for (int nt = 0; nt < 4; ++nt) s = fmaf(acc[mt][nt][r], acc[mt][nt][r], s);
                s += __shfl_xor(s, 1);
                s += __shfl_xor(s, 2);
                s += __shfl_xor(s, 4);
                s += __shfl_xor(s, 8);
                if (lx == 0) {
                    const int m = m0 + wm * 64 + mt * 16 + q4 * 4 + r;
                    Np[(size_t)((m >> 11) * HH + head) * NN + (m & 2047)] = s;
                }
            }
    }

    // epilogue: C row m = q4*4+reg, col j = lx (verified mapping)
    #pragma unroll
    for (int mt = 0; mt < 4; ++mt) {
        #pragma unroll
        for (int r = 0; r < 4; ++r) {
            const int m = m0 + wm * 64 + mt * 16 + q4 * 4 + r;
            const int b = m >> 11, n2 = m & 2047;
            #pragma unroll
            for (int nt = 0; nt < 4; ++nt) {
                const int j = n0 + wn * 64 + nt * 16 + lx;
                const float v = acc[mt][nt][r];
                if (mode == 3) {
                    Outp[(size_t)m * DDIM + j] = v;
                } else {
                    const size_t idx = (((size_t)(b * HH + (j >> 6)) * NN + n2) << 6) + (j & 63);
                    if (mode == 2) {
                        Vb[idx] = f2bf(v);
                    } else {
                        const unsigned short h = f2bf(v);
                        const unsigned short l = f2bf(v - bf2f(h));
                        if (mode == 0) { Qhi[idx] = h; Qlo[idx] = l; }
                        else           { Khi[idx] = h; Klo[idx] = l; }
                    }
                }
            }
        }
    }
}

// ---------------------------------------------------------------------------
// V transpose: Vb [B,H,N,64] bf16 -> Vt [B,H,64,N] bf16 (for MFMA B-fragments)
// ---------------------------------------------------------------------------
__global__ __launch_bounds__(256)
void v_transpose(const unsigned short* __restrict__ Vb, unsigned short* __restrict__ Vt)
{
    __shared__ unsigned short T[64 * LDK];
    const int id = blockIdx.x;          // 512 = 16 bh * 32 n-tiles
    const int bh = id >> 5, nt = id & 31;
    const size_t ibase = (((size_t)bh * NN + nt * 64) << 6);
    const int row = threadIdx.x >> 2, ch = threadIdx.x & 3;

    #pragma unroll
    for (int half = 0; half < 2; ++half) {
        const int col = ch * 8 + half * 32;
        *(uint4*)&T[row * LDK + col] = *(const uint4*)(Vb + ibase + (row << 6) + col);
    }
    __syncthreads();

    const size_t obase = (size_t)bh * 64 * NN;
    #pragma unroll
    for (int half = 0; half < 2; ++half) {
        const int col = ch * 8 + half * 32;
        union { unsigned short u[8]; uint4 v; } tmp;
        #pragma unroll
        for (int j = 0; j < 8; ++j) tmp.u[j] = T[(col + j) * LDK + row];
        *(uint4*)(Vt + obase + (size_t)row * NN + nt * 64 + col) = tmp.v;
    }
}

// ---------------------------------------------------------------------------
// MFMA flash attention, FLASH-DECODING SPLIT: each block owns (bh, qt, chunk)
// where a chunk is 8 k-tiles (512 keys). 80 chunks/bh x 16 bh = 1280 uniform
// blocks (vs 512 variable) -> occupancy 2 -> ~5 waves/SIMD, no tail imbalance.
// Partial (O, m, l) written fp32 to workspace; attn_combine merges <=4 slots.
// ---------------------------------------------------------------------------
__global__ __launch_bounds__(256, 2)
void attn_mfma(const unsigned short* __restrict__ Qhi, const unsigned short* __restrict__ Qlo,
               const unsigned short* __restrict__ Khi, const unsigned short* __restrict__ Klo,
               const unsigned short* __restrict__ Vt,
               const float* __restrict__ QN, const float* __restrict__ KN,
               const float* __restrict__ pLC, const float* __restrict__ pLB,
               float* __restrict__ Opart, float* __restrict__ Mp, float* __restrict__ Lp)
{
    __shared__ unsigned short Kh_s[64 * LDK];
    __shared__ unsigned short Kl_s[64 * LDK];
    __shared__ unsigned short Vt_s[64 * LDK];
    __shared__ unsigned short P_s [64 * LDK];
    __shared__ float kn_s[64];
    __shared__ float qn_s[64];

    // decode (qt, chunk) from blockIdx.x in [0,80): group g = qt>>3 has g+1
    // chunks per qt; group base = 4g(g+1).
    const int idx = blockIdx.x;
    const int g   = (idx >= 48) ? 3 : (idx >= 24) ? 2 : (idx >= 8) ? 1 : 0;
    const int rem = idx - 4 * g * (g + 1);
    const int qt  = g * 8 + rem / (g + 1);
    const int c0  = rem % (g + 1);
    const int bh  = blockIdx.y;
    const int kt0 = c0 * 8;
    const int kend = min(kt0 + 8, qt + 1);

    const int tid  = threadIdx.x;
    const int w    = tid >> 6;
    const int lane = tid & 63;
    const int lx   = lane & 15;
    const int q4   = lane >> 4;

    const float hc   = softplus_f(pLC[0]);
    const float beta = softplus_f(pLB[0]) + 0.5f;

    const size_t base = ((size_t)bh * NN) << 6;

    // Q fragments (A-layout: m=lx, k=q4*8+j), held in registers
    const unsigned short* qrh = Qhi + base + ((size_t)(qt * 64 + w * 16 + lx) << 6) + q4 * 8;
    const unsigned short* qrl = Qlo + base + ((size_t)(qt * 64 + w * 16 + lx) << 6) + q4 * 8;
    const bf16x8 qh0 = *(const bf16x8*)(qrh);
    const bf16x8 qh1 = *(const bf16x8*)(qrh + 32);
    const bf16x8 ql0 = *(const bf16x8*)(qrl);
    const bf16x8 ql1 = *(const bf16x8*)(qrl + 32);

    if (tid < 64) qn_s[tid] = QN[(size_t)bh * NN + qt * 64 + tid];

    f32x4 Oacc[4];
    float m_st[4], l_st[4];
    #pragma unroll
    for (int r = 0; r < 4; ++r) {
        m_st[r] = -INFINITY; l_st[r] = 0.f;
        Oacc[r] = (f32x4){0.f, 0.f, 0.f, 0.f};
    }

    const int srow = tid >> 2, sch = tid & 3;

    // prefetch first tile (kt0)
    uint4 pKh0, pKh1, pKl0, pKl1, pVt0, pVt1; float pkn = 0.f;
    {
        const unsigned short* kh = Khi + base + ((size_t)(kt0 * 64 + srow) << 6);
        const unsigned short* kl = Klo + base + ((size_t)(kt0 * 64 + srow) << 6);
        const unsigned short* vt = Vt  + base + (size_t)srow * NN + kt0 * 64;
        pKh0 = *(const uint4*)(kh + sch * 8);  pKh1 = *(const uint4*)(kh + sch * 8 + 32);
        pKl0 = *(const uint4*)(kl + sch * 8);  pKl1 = *(const uint4*)(kl + sch * 8 + 32);
        pVt0 = *(const uint4*)(vt + sch * 8);  pVt1 = *(const uint4*)(vt + sch * 8 + 32);
        if (tid < 64) pkn = KN[(size_t)bh * NN + kt0 * 64 + tid];
    }

    __syncthreads();   // qn_s visible

    for (int kt = kt0; kt < kend; ++kt) {
        // ---- commit prefetched tile to LDS ----
        *(uint4*)&Kh_s[srow * LDK + sch * 8]      = pKh0;
        *(uint4*)&Kh_s[srow * LDK + sch * 8 + 32] = pKh1;
        *(uint4*)&Kl_s[srow * LDK + sch * 8]      = pKl0;
        *(uint4*)&Kl_s[srow * LDK + sch * 8 + 32] = pKl1;
        *(uint4*)&Vt_s[srow * LDK + sch * 8]      = pVt0;
        *(uint4*)&Vt_s[srow * LDK + sch * 8 + 32] = pVt1;
        if (tid < 64) kn_s[tid] = pkn;
        __syncthreads();

        // ---- prefetch tile kt+1 (in flight during compute) ----
        if (kt + 1 < kend) {
            const unsigned short* kh = Khi + base + ((size_t)((kt + 1) * 64 + srow) << 6);
            const unsigned short* kl = Klo + base + ((size_t)((kt + 1) * 64 + srow) << 6);
            const unsigned short* vt = Vt  + base + (size_t)srow * NN + (kt + 1) * 64;
            pKh0 = *(const uint4*)(kh + sch * 8);  pKh1 = *(const uint4*)(kh + sch * 8 + 32);
            pKl0 = *(const uint4*)(kl + sch * 8);  pKl1 = *(const uint4*)(kl + sch * 8 + 32);
            pVt0 = *(const uint4*)(vt + sch * 8);  pVt1 = *(const uint4*)(vt + sch * 8 + 32);
            if (tid < 64) pkn = KN[(size_t)bh * NN + (kt + 1) * 64 + tid];
        }

        // ---- S = Q K^T (hi/lo compensated) ----
        f32x4 S[4];
        #pragma unroll
        for (int t = 0; t < 4; ++t) {
            f32x4 acc = (f32x4){0.f, 0.f, 0.f, 0.f};
            #pragma unroll
            for (int c2 = 0; c2 < 2; ++c2) {
                const int off = (t * 16 + lx) * LDK + c2 * 32 + q4 * 8;
                const bf16x8 kh = *(const bf16x8*)&Kh_s[off];
                const bf16x8 kl = *(const bf16x8*)&Kl_s[off];
                const bf16x8 qh = c2 ? qh1 : qh0;
                const bf16x8 ql = c2 ? ql1 : ql0;
                acc = __builtin_amdgcn_mfma_f32_16x16x32_bf16(qh, kh, acc, 0, 0, 0);
                acc = __builtin_amdgcn_mfma_f32_16x16x32_bf16(qh, kl, acc, 0, 0, 0);
                acc = __builtin_amdgcn_mfma_f32_16x16x32_bf16(ql, kh, acc, 0, 0, 0);
            }
            S[t] = acc;
        }

        // ---- hyperbolic distance -> scores, online softmax ----
        float qn_r[4];
        #pragma unroll
        for (int r = 0; r < 4; ++r) qn_r[r] = qn_s[w * 16 + q4 * 4 + r];
        const bool diag = (kt == qt);

        float mrow[4] = {-INFINITY, -INFINITY, -INFINITY, -INFINITY};
        #pragma unroll
        for (int t = 0; t < 4; ++t) {
            const float kn = kn_s[t * 16 + lx];
            #pragma unroll
            for (int r = 0; r < 4; ++r) {
                const float sumn = qn_r[r] + kn;
                float diff = fmaxf(fmaf(-2.f, S[t][r], sumn), 0.f);
                float s = -beta * sqrtf(fmaf(hc, sumn, 1.f) * (diff + 1e-8f));
                const int cc = t * 16 + lx;
                const int rr = w * 16 + q4 * 4 + r;
                if (diag && cc > rr) s = -INFINITY;
                S[t][r] = s;
                mrow[r] = fmaxf(mrow[r], s);
            }
        }

        #pragma unroll
        for (int r = 0; r < 4; ++r) {
            float m = mrow[r];
            m = fmaxf(m, __shfl_xor(m, 1));
            m = fmaxf(m, __shfl_xor(m, 2));
            m = fmaxf(m, __shfl_xor(m, 4));
            m = fmaxf(m, __shfl_xor(m, 8));
            const float mn = fmaxf(m_st[r], m);
            const float al = __expf(m_st[r] - mn);
            m_st[r] = mn;
            float rs = 0.f;
            #pragma unroll
            for (int t = 0; t < 4; ++t) {
                const float p = __expf(S[t][r] - mn);
                rs += p;
                P_s[(w * 16 + q4 * 4 + r) * LDK + t * 16 + lx] = f2bf(p);
            }
            rs += __shfl_xor(rs, 1);
            rs += __shfl_xor(rs, 2);
            rs += __shfl_xor(rs, 4);
            rs += __shfl_xor(rs, 8);
            l_st[r] = l_st[r] * al + rs;
            #pragma unroll
            for (int t = 0; t < 4; ++t) Oacc[t][r] *= al;
        }

        // P_s is wave-local (rows [16w,16w+16) written and read by wave w);
        // same-wave DS ops are pipe-ordered — no __syncthreads needed.
        __builtin_amdgcn_wave_barrier();

        // ---- O += P V ----
        #pragma unroll
        for (int c2 = 0; c2 < 2; ++c2) {
            const bf16x8 pa = *(const bf16x8*)&P_s[(w * 16 + lx) * LDK + c2 * 32 + q4 * 8];
            #pragma unroll
            for (int t = 0; t < 4; ++t) {
                const bf16x8 vb = *(const bf16x8*)&Vt_s[(t * 16 + lx) * LDK + c2 * 32 + q4 * 8];
                Oacc[t] = __builtin_amdgcn_mfma_f32_16x16x32_bf16(pa, vb, Oacc[t], 0, 0, 0);
            }
        }
        __syncthreads();   // all waves done reading K/Vt before next commit
    }

    // ---- epilogue: write unnormalized fp32 partial + (m, l) to slot ----
    const int slot = ((bh * 32 + qt) << 2) + c0;
    float* op = Opart + ((size_t)slot << 12);
    #pragma unroll
    for (int r = 0; r < 4; ++r) {
        const int row = w * 16 + q4 * 4 + r;
        #pragma unroll
        for (int t = 0; t < 4; ++t)
            op[row * 64 + t * 16 + lx] = Oacc[t][r];
        if (lx == 0) {
            Mp[slot * 64 + row] = m_st[r];
            Lp[slot * 64 + row] = l_st[r];
        }
    }
}

// ---------------------------------------------------------------------------
// Combine <=4 chunk partials per (bh, qt): out = sum_c e^{m_c-M} O_c / L,
// emits AO as bf16 hi/lo in [B,H,N,64].
// ---------------------------------------------------------------------------
__global__ __launch_bounds__(256)
void attn_combine(const float* __restrict__ Opart, const float* __restrict__ Mp,
                  const float* __restrict__ Lp,
                  unsigned short* __restrict__ AOh, unsigned short* __restrict__ AOl)
{
    const int bh = blockIdx.x >> 5, qt = blockIdx.x & 31;
    const int C = (qt >> 3) + 1;
    const int row = threadIdx.x >> 2, qd = threadIdx.x & 3;
    const int slot0 = (bh * 32 + qt) << 2;

    float m = -INFINITY;
    for (int c = 0; c < C; ++c) m = fmaxf(m, Mp[(slot0 + c) * 64 + row]);
    float L = 0.f;
    float o[16];
    #pragma unroll
    for (int j = 0; j < 16; ++j) o[j] = 0.f;

    for (int c = 0; c < C; ++c) {
        const float wgt = __expf(Mp[(slot0 + c) * 64 + row] - m);
        L += wgt * Lp[(slot0 + c) * 64 + row];
        const float* op = Opart + (((size_t)(slot0 + c)) << 12) + row * 64 + qd * 16;
        #pragma unroll
        for (int j4 = 0; j4 < 4; ++j4) {
            float4 v = *(const float4*)(op + j4 * 4);
            o[j4*4+0] = fmaf(wgt, v.x, o[j4*4+0]);
            o[j4*4+1] = fmaf(wgt, v.y, o[j4*4+1]);
            o[j4*4+2] = fmaf(wgt, v.z, o[j4*4+2]);
            o[j4*4+3] = fmaf(wgt, v.w, o[j4*4+3]);
        }
    }

    const float inv = 1.f / L;
    const size_t obase = (((size_t)bh * NN + qt * 64 + row) << 6) + qd * 16;
    union { unsigned short u[8]; uint4 v; } h2[2], l2[2];
    #pragma unroll
    for (int j = 0; j < 16; ++j) {
        const float ov = o[j] * inv;
        const unsigned short h = f2bf(ov);
        const unsigned short l = f2bf(ov - bf2f(h));
        h2[j >> 3].u[j & 7] = h;
        l2[j >> 3].u[j & 7] = l;
    }
    *(uint4*)(AOh + obase)     = h2[0].v;
    *(uint4*)(AOh + obase + 8) = h2[1].v;
    *(uint4*)(AOl + obase)     = l2[0].v;
    *(uint4*)(AOl + obase + 8) = l2[1].v;
}

// ---------------------------------------------------------------------------
extern "C" void kernel_launch(void* const* d_in, const int* in_sizes, int n_in,
                              void* d_out, int out_size, void* d_ws, size_t ws_size,
                              hipStream_t stream)
{
    const float* x        = (const float*)d_in[0];
    const float* Wq       = (const float*)d_in[1];
    const float* Wk       = (const float*)d_in[2];
    const float* Wv       = (const float*)d_in[3];
    const float* Wo       = (const float*)d_in[4];
    const float* log_c    = (const float*)d_in[5];
    const float* log_beta = (const float*)d_in[6];
    float* out = (float*)d_out;

    unsigned short* p = (unsigned short*)d_ws;
    unsigned short* xh  = p;            p += EE;
    unsigned short* xl  = p;            p += EE;
    unsigned short* wqh = p;            p += WN;
    unsigned short* wql = p;            p += WN;
    unsigned short* wkh = p;            p += WN;
    unsigned short* wkl = p;            p += WN;
    unsigned short* wvh = p;            p += WN;
    unsigned short* wvl = p;            p += WN;
    unsigned short* woh = p;            p += WN;
    unsigned short* wol = p;            p += WN;
    unsigned short* Qhi = p;            p += EE;
    unsigned short* Qlo = p;            p += EE;
    unsigned short* Khi = p;            p += EE;
    unsigned short* Klo = p;            p += EE;
    unsigned short* Vb  = p;            p += EE;
    unsigned short* Vtr = p;            p += EE;
    unsigned short* AOh = p;            p += EE;
    unsigned short* AOl = p;            p += EE;
    float* QN    = (float*)p;
    float* KN    = QN + (size_t)BB * HH * NN;
    float* Opart = KN + (size_t)BB * HH * NN;                 // 2048 x 4096 fp32
    float* Mp    = Opart + (size_t)NSLOT * 64 * 64;
    float* Lp    = Mp + (size_t)NSLOT * 64;

    split_hl   <<<dim3(256, 5), 256, 0, stream>>>(x, Wq, Wk, Wv, Wo,
                                                  xh, xl, wqh, wql, wkh, wkl, wvh, wvl, woh, wol);
    mm_mfma    <<<dim3(MTOT / 128, 4, 3), 256, 0, stream>>>(xh, xl,
                                                  wqh, wql, wkh, wkl, wvh, wvl, 0,
                                                  Qhi, Qlo, Khi, Klo, Vb, nullptr, QN, KN);
    v_transpose<<<dim3(512), 256, 0, stream>>>(Vb, Vtr);
    attn_mfma  <<<dim3(80, 16), 256, 0, stream>>>(Qhi, Qlo, Khi, Klo, Vtr, QN, KN,
                                                  log_c, log_beta, Opart, Mp, Lp);
    attn_combine<<<dim3(512), 256, 0, stream>>>(Opart, Mp, Lp, AOh, AOl);
    mm_mfma    <<<dim3(MTOT / 128, 4, 1), 256, 0, stream>>>(AOh, AOl,
                                                  woh, wol, nullptr, nullptr, nullptr, nullptr, 1,
                                                  nullptr, nullptr, nullptr, nullptr, nullptr, out,
                                                  nullptr, nullptr);
}